// Round 1
// baseline (340.034 us; speedup 1.0000x reference)
//
#include <hip/hip_runtime.h>
#include <math.h>

#define N_EMBD    4096
#define N_EXPERTS 64
#define N_TOKENS  16384   // 4 * 4096
#define T_WAVE    16      // tokens per wave
#define K_HALF    2048    // K split in two halves across waves

// ---------------------------------------------------------------------------
// Kernel 0: pack W [64][4096] f32 -> Wt4 [1024][64] float4
//   Wt4[k4][e] = W[e][4*k4 .. 4*k4+3]
// so that lane e loading Wt4[k4*64 + e] is a perfectly coalesced 1KB wave load.
// ---------------------------------------------------------------------------
__global__ void wt_pack(const float* __restrict__ W, float4* __restrict__ Wt4) {
    int tid = blockIdx.x * blockDim.x + threadIdx.x;   // 65536 total
    int e  = tid >> 10;        // 0..63
    int k4 = tid & 1023;       // 0..1023
    float4 v = ((const float4*)W)[e * 1024 + k4];      // coalesced read per row
    Wt4[k4 * 64 + e] = v;
}

// ---------------------------------------------------------------------------
// Kernel 1: main GEMM. Wave = 64 lanes = 64 experts. Each wave handles
// T_WAVE tokens over one K-half. x loads are wave-uniform (scalar path);
// W loads are per-lane coalesced float4. 4 striped sub-accumulators per token
// keep f32 rounding error low (top-2 index stability vs np reference).
// partial layout: [2][N_TOKENS][64] f32
// ---------------------------------------------------------------------------
__global__ __launch_bounds__(256, 2) void router_gemm(
        const float* __restrict__ x,
        const float4* __restrict__ Wt4,
        float* __restrict__ partial) {
    const int lane = threadIdx.x & 63;
    const int wid  = __builtin_amdgcn_readfirstlane((blockIdx.x << 2) + (threadIdx.x >> 6));
    const int kh   = wid & 1;            // which K-half
    const int tg   = wid >> 1;           // token group 0..1023
    const int tok0 = tg * T_WAVE;

    const float* xbase = x + (size_t)tok0 * N_EMBD + kh * K_HALF;

    float acc[T_WAVE][4];
#pragma unroll
    for (int t = 0; t < T_WAVE; ++t)
#pragma unroll
        for (int j = 0; j < 4; ++j) acc[t][j] = 0.0f;

    const int k4h = (kh * K_HALF) >> 2;  // float4 index base of this K-half

    for (int kc = 0; kc < K_HALF; kc += 16) {
        const int k4 = k4h + (kc >> 2);
        // per-lane W fragments for 16 consecutive k (4 float4)
        float4 w0 = Wt4[(k4 + 0) * 64 + lane];
        float4 w1 = Wt4[(k4 + 1) * 64 + lane];
        float4 w2 = Wt4[(k4 + 2) * 64 + lane];
        float4 w3 = Wt4[(k4 + 3) * 64 + lane];
#pragma unroll
        for (int t = 0; t < T_WAVE; ++t) {
            const float4* xr = (const float4*)(xbase + (size_t)t * N_EMBD + kc);
            float4 x0 = xr[0];
            float4 x1 = xr[1];
            float4 x2 = xr[2];
            float4 x3 = xr[3];
            acc[t][0] = fmaf(w0.x, x0.x, acc[t][0]);
            acc[t][0] = fmaf(w0.y, x0.y, acc[t][0]);
            acc[t][0] = fmaf(w0.z, x0.z, acc[t][0]);
            acc[t][0] = fmaf(w0.w, x0.w, acc[t][0]);
            acc[t][1] = fmaf(w1.x, x1.x, acc[t][1]);
            acc[t][1] = fmaf(w1.y, x1.y, acc[t][1]);
            acc[t][1] = fmaf(w1.z, x1.z, acc[t][1]);
            acc[t][1] = fmaf(w1.w, x1.w, acc[t][1]);
            acc[t][2] = fmaf(w2.x, x2.x, acc[t][2]);
            acc[t][2] = fmaf(w2.y, x2.y, acc[t][2]);
            acc[t][2] = fmaf(w2.z, x2.z, acc[t][2]);
            acc[t][2] = fmaf(w2.w, x2.w, acc[t][2]);
            acc[t][3] = fmaf(w3.x, x3.x, acc[t][3]);
            acc[t][3] = fmaf(w3.y, x3.y, acc[t][3]);
            acc[t][3] = fmaf(w3.z, x3.z, acc[t][3]);
            acc[t][3] = fmaf(w3.w, x3.w, acc[t][3]);
        }
    }

#pragma unroll
    for (int t = 0; t < T_WAVE; ++t) {
        float s = (acc[t][0] + acc[t][1]) + (acc[t][2] + acc[t][3]);
        partial[((size_t)kh * N_TOKENS + (tok0 + t)) * 64 + lane] = s;
    }
}

// ---------------------------------------------------------------------------
// Kernel 2: per-token finalize. One wave per token (lane = expert).
// Sum the two K-half partials, top-2 via butterfly argmax (min-index
// tie-break, matching lax.top_k), softmax over the 2 values.
// Output: out[0 .. 2*N_TOKENS) = indices (as float), then gates.
// ---------------------------------------------------------------------------
__global__ void finalize(const float* __restrict__ partial, float* __restrict__ out) {
    const int lane = threadIdx.x & 63;
    const int tok  = blockIdx.x * (blockDim.x >> 6) + (threadIdx.x >> 6);
    if (tok >= N_TOKENS) return;

    float v = partial[(size_t)tok * 64 + lane]
            + partial[((size_t)N_TOKENS + tok) * 64 + lane];

    // top-1 (all-lanes butterfly; ties -> smaller index)
    float m1 = v; int i1 = lane;
#pragma unroll
    for (int off = 32; off >= 1; off >>= 1) {
        float ov = __shfl_xor(m1, off);
        int   oi = __shfl_xor(i1, off);
        if (ov > m1 || (ov == m1 && oi < i1)) { m1 = ov; i1 = oi; }
    }
    // top-2: exclude winner lane
    float m2 = (lane == i1) ? -INFINITY : v;
    int   i2 = lane;
#pragma unroll
    for (int off = 32; off >= 1; off >>= 1) {
        float ov = __shfl_xor(m2, off);
        int   oi = __shfl_xor(i2, off);
        if (ov > m2 || (ov == m2 && oi < i2)) { m2 = ov; i2 = oi; }
    }

    if (lane == 0) {
        float e2 = __expf(m2 - m1);            // m2 <= m1
        float inv = 1.0f / (1.0f + e2);
        out[2 * tok + 0] = (float)i1;
        out[2 * tok + 1] = (float)i2;
        out[2 * N_TOKENS + 2 * tok + 0] = inv;        // gate of top-1
        out[2 * N_TOKENS + 2 * tok + 1] = e2 * inv;   // gate of top-2
    }
}

// ---------------------------------------------------------------------------
extern "C" void kernel_launch(void* const* d_in, const int* in_sizes, int n_in,
                              void* d_out, int out_size, void* d_ws, size_t ws_size,
                              hipStream_t stream) {
    const float* x = (const float*)d_in[0];
    const float* W = (const float*)d_in[1];
    float* out = (float*)d_out;

    float4* Wt4    = (float4*)d_ws;                       // 1 MB
    float*  partial = (float*)((char*)d_ws + (1 << 20));  // 8 MB ([2][16384][64] f32)

    // pack W
    wt_pack<<<256, 256, 0, stream>>>(W, Wt4);
    // main GEMM: 2048 waves = 512 blocks x 4 waves
    router_gemm<<<512, 256, 0, stream>>>(x, Wt4, partial);
    // finalize: one wave per token, 4 tokens per block
    finalize<<<N_TOKENS / 4, 256, 0, stream>>>(partial, out);
}

// Round 2
// 132.089 us; speedup vs baseline: 2.5743x; 2.5743x over previous
//
#include <hip/hip_runtime.h>
#include <math.h>

#define N_EMBD    4096
#define N_EXPERTS 64
#define N_TOKENS  16384
#define TAU       1e-3f

typedef __attribute__((ext_vector_type(8))) short bf16x8;
typedef __attribute__((ext_vector_type(4))) float f32x4;

#define MFMA16 __builtin_amdgcn_mfma_f32_16x16x32_bf16

// ---------------------------------------------------------------------------
// f32 -> (bf16 hi, bf16 lo) split, RNE, pair-packed into one u32 each.
// x = hi + lo + err, |err| <= 2^-18 |x| approx. Inputs are finite Gaussians.
// ---------------------------------------------------------------------------
__device__ __forceinline__ void split_pair(float f0, float f1,
                                           unsigned& hpack, unsigned& lpack) {
    unsigned u0 = __builtin_bit_cast(unsigned, f0);
    unsigned u1 = __builtin_bit_cast(unsigned, f1);
    unsigned r0 = u0 + 0x7FFFu + ((u0 >> 16) & 1u);
    unsigned r1 = u1 + 0x7FFFu + ((u1 >> 16) & 1u);
    hpack = (r0 >> 16) | (r1 & 0xFFFF0000u);
    float h0 = __builtin_bit_cast(float, r0 & 0xFFFF0000u);
    float h1 = __builtin_bit_cast(float, r1 & 0xFFFF0000u);
    float l0 = f0 - h0;           // exact (Sterbenz)
    float l1 = f1 - h1;
    unsigned v0 = __builtin_bit_cast(unsigned, l0);
    unsigned v1 = __builtin_bit_cast(unsigned, l1);
    unsigned s0 = v0 + 0x7FFFu + ((v0 >> 16) & 1u);
    unsigned s1 = v1 + 0x7FFFu + ((v1 >> 16) & 1u);
    lpack = (s0 >> 16) | (s1 & 0xFFFF0000u);
}

// ---------------------------------------------------------------------------
// Kernel 0: pack W [64][4096] f32 -> Wt4 [1024][64] float4 (for refine).
// ---------------------------------------------------------------------------
__global__ void wt_pack(const float* __restrict__ W, float4* __restrict__ Wt4) {
    int tid = blockIdx.x * blockDim.x + threadIdx.x;   // 65536
    int e  = tid >> 10;
    int k4 = tid & 1023;
    Wt4[k4 * 64 + e] = ((const float4*)W)[e * 1024 + k4];
}

// ---------------------------------------------------------------------------
// Kernel 1: pack W into bf16 hi/lo MFMA B-fragments.
// Frag F = ks*8 + nt*2 + term (ks=K-step of 32, nt=expert tile of 16,
// term 0=hi 1=lo). Lane l, elem j holds W[nt*16+(l&15)][ks*32+(l>>4)*8+j].
// Stored as Bpack[F*64 + lane] (uint4 = 8 bf16). Also zeroes the flag count.
// ---------------------------------------------------------------------------
__global__ void w_pack_bf16(const float* __restrict__ W,
                            uint4* __restrict__ Bpack,
                            int* __restrict__ flags) {
    int tid = blockIdx.x * blockDim.x + threadIdx.x;   // 32768
    if (tid == 0) flags[0] = 0;
    int lane = tid & 63;
    int nt   = (tid >> 6) & 3;
    int ks   = tid >> 8;                               // 0..127
    int e = nt * 16 + (lane & 15);
    int k = ks * 32 + ((lane >> 4) << 3);
    const float* src = W + (size_t)e * N_EMBD + k;     // 8 consecutive f32
    uint4 hp, lp;
    split_pair(src[0], src[1], hp.x, lp.x);
    split_pair(src[2], src[3], hp.y, lp.y);
    split_pair(src[4], src[5], hp.z, lp.z);
    split_pair(src[6], src[7], hp.w, lp.w);
    size_t F = (size_t)ks * 8 + nt * 2;
    Bpack[F * 64 + lane]       = hp;
    Bpack[(F + 1) * 64 + lane] = lp;
}

// ---------------------------------------------------------------------------
// One K-step of compute: split A to hi/lo frags, 12 MFMAs (4 N-tiles x 3 terms)
// ---------------------------------------------------------------------------
__device__ __forceinline__ void compute_step(
        float4 A0, float4 A1,
        uint4 B0, uint4 B1, uint4 B2, uint4 B3,
        uint4 B4, uint4 B5, uint4 B6, uint4 B7,
        f32x4& c0, f32x4& c1, f32x4& c2, f32x4& c3) {
    uint4 hu, lu;
    split_pair(A0.x, A0.y, hu.x, lu.x);
    split_pair(A0.z, A0.w, hu.y, lu.y);
    split_pair(A1.x, A1.y, hu.z, lu.z);
    split_pair(A1.z, A1.w, hu.w, lu.w);
    bf16x8 ah = __builtin_bit_cast(bf16x8, hu);
    bf16x8 al = __builtin_bit_cast(bf16x8, lu);
    bf16x8 bh, bl;
    bh = __builtin_bit_cast(bf16x8, B0); bl = __builtin_bit_cast(bf16x8, B1);
    c0 = MFMA16(ah, bh, c0, 0, 0, 0);
    c0 = MFMA16(ah, bl, c0, 0, 0, 0);
    c0 = MFMA16(al, bh, c0, 0, 0, 0);
    bh = __builtin_bit_cast(bf16x8, B2); bl = __builtin_bit_cast(bf16x8, B3);
    c1 = MFMA16(ah, bh, c1, 0, 0, 0);
    c1 = MFMA16(ah, bl, c1, 0, 0, 0);
    c1 = MFMA16(al, bh, c1, 0, 0, 0);
    bh = __builtin_bit_cast(bf16x8, B4); bl = __builtin_bit_cast(bf16x8, B5);
    c2 = MFMA16(ah, bh, c2, 0, 0, 0);
    c2 = MFMA16(ah, bl, c2, 0, 0, 0);
    c2 = MFMA16(al, bh, c2, 0, 0, 0);
    bh = __builtin_bit_cast(bf16x8, B6); bl = __builtin_bit_cast(bf16x8, B7);
    c3 = MFMA16(ah, bh, c3, 0, 0, 0);
    c3 = MFMA16(ah, bl, c3, 0, 0, 0);
    c3 = MFMA16(al, bh, c3, 0, 0, 0);
}

// ---------------------------------------------------------------------------
// Kernel 2: main MFMA GEMM. Block = 4 waves, same K-half, 4 consecutive
// token-groups (so B-frag loads L1-hit across waves; per-step barrier keeps
// them in lockstep). Wave = 16 tokens x 64 experts x K-half(2048).
// partial layout: [2][N_TOKENS][64] f32.
// ---------------------------------------------------------------------------
__global__ __launch_bounds__(256, 2) void router_mfma(
        const float* __restrict__ x,
        const uint4* __restrict__ Bpack,
        float* __restrict__ partial) {
    const int lane = threadIdx.x & 63;
    const int wv   = threadIdx.x >> 6;
    const int kh   = blockIdx.x & 1;
    const int tg   = (blockIdx.x >> 1) * 4 + wv;       // 0..1023
    const int tok0 = tg * 16;

    const float4* pa = (const float4*)(x + (size_t)(tok0 + (lane & 15)) * N_EMBD
                                         + kh * 2048 + ((lane >> 4) << 3));
    const uint4* pb = Bpack + (size_t)(kh * 64 * 8) * 64 + lane;

    f32x4 acc0 = {0.f,0.f,0.f,0.f}, acc1 = {0.f,0.f,0.f,0.f};
    f32x4 acc2 = {0.f,0.f,0.f,0.f}, acc3 = {0.f,0.f,0.f,0.f};

    uint4 ba0, ba1, ba2, ba3, ba4, ba5, ba6, ba7;
    uint4 bb0, bb1, bb2, bb3, bb4, bb5, bb6, bb7;
    float4 a0a, a1a, a0b, a1b;

#define LOADB(P, s) { const uint4* _q = pb + (size_t)(s) * 512;               \
    P##0 = _q[0];   P##1 = _q[64];  P##2 = _q[128]; P##3 = _q[192];           \
    P##4 = _q[256]; P##5 = _q[320]; P##6 = _q[384]; P##7 = _q[448]; }
#define LOADA(A0, A1, s) { A0 = pa[(s) * 8]; A1 = pa[(s) * 8 + 1]; }

    LOADB(ba, 0); LOADA(a0a, a1a, 0);
    for (int s = 0; s < 64; s += 2) {
        LOADB(bb, s + 1); LOADA(a0b, a1b, s + 1);
        compute_step(a0a, a1a, ba0, ba1, ba2, ba3, ba4, ba5, ba6, ba7,
                     acc0, acc1, acc2, acc3);
        __syncthreads();
        if (s < 62) { LOADB(ba, s + 2); LOADA(a0a, a1a, s + 2); }
        compute_step(a0b, a1b, bb0, bb1, bb2, bb3, bb4, bb5, bb6, bb7,
                     acc0, acc1, acc2, acc3);
        __syncthreads();
    }
#undef LOADB
#undef LOADA

    // C/D layout (m89-verified): col = lane&15, row = (lane>>4)*4 + reg
    const int rb = (lane >> 4) << 2;
    float* po = partial + ((size_t)kh * N_TOKENS + tok0) * 64 + (lane & 15);
#pragma unroll
    for (int j = 0; j < 4; ++j) {
        size_t r = (size_t)(rb + j) * 64;
        po[r +  0] = acc0[j];
        po[r + 16] = acc1[j];
        po[r + 32] = acc2[j];
        po[r + 48] = acc3[j];
    }
}

// ---------------------------------------------------------------------------
// Kernel 3: finalize. Wave per token; top-3 butterflies; softmax of top-2;
// flag near-tie tokens (gap12 or gap23 < TAU) for exact refinement.
// ---------------------------------------------------------------------------
__global__ void finalize(const float* __restrict__ partial,
                         float* __restrict__ out,
                         int* __restrict__ flags) {
    const int lane = threadIdx.x & 63;
    const int tok  = blockIdx.x * 4 + (threadIdx.x >> 6);

    float v = partial[(size_t)tok * 64 + lane]
            + partial[((size_t)N_TOKENS + tok) * 64 + lane];

    float m1 = v; int i1 = lane;
#pragma unroll
    for (int off = 32; off; off >>= 1) {
        float ov = __shfl_xor(m1, off); int oi = __shfl_xor(i1, off);
        if (ov > m1 || (ov == m1 && oi < i1)) { m1 = ov; i1 = oi; }
    }
    float m2 = (lane == i1) ? -INFINITY : v; int i2 = lane;
#pragma unroll
    for (int off = 32; off; off >>= 1) {
        float ov = __shfl_xor(m2, off); int oi = __shfl_xor(i2, off);
        if (ov > m2 || (ov == m2 && oi < i2)) { m2 = ov; i2 = oi; }
    }
    float m3 = (lane == i1 || lane == i2) ? -INFINITY : v;
#pragma unroll
    for (int off = 32; off; off >>= 1)
        m3 = fmaxf(m3, __shfl_xor(m3, off));

    if (lane == 0) {
        float e2  = __expf(m2 - m1);
        float inv = 1.0f / (1.0f + e2);
        out[2 * tok + 0] = (float)i1;
        out[2 * tok + 1] = (float)i2;
        out[2 * N_TOKENS + 2 * tok + 0] = inv;
        out[2 * N_TOKENS + 2 * tok + 1] = e2 * inv;
        if ((m1 - m2 < TAU) || (m2 - m3 < TAU)) {
            int p = atomicAdd(flags, 1);
            if (p < N_TOKENS) flags[1 + p] = tok;
        }
    }
}

// ---------------------------------------------------------------------------
// Kernel 4: exact refinement of flagged tokens. Block per token (strided),
// 4 waves split K, f64 accumulation, LDS combine, exact top-2 + gates.
// ---------------------------------------------------------------------------
__global__ __launch_bounds__(256) void refine(const float* __restrict__ x,
                                              const float4* __restrict__ Wt4,
                                              const int* __restrict__ flags,
                                              float* __restrict__ out) {
    __shared__ double red[4][64];
    const int lane = threadIdx.x & 63;
    const int wv   = threadIdx.x >> 6;
    int cnt = flags[0];
    if (cnt > N_TOKENS) cnt = N_TOKENS;

    for (int i = blockIdx.x; i < cnt; i += gridDim.x) {
        const int tok = flags[1 + i];
        const float4* xr = (const float4*)(x + (size_t)tok * N_EMBD) + wv * 256;
        const float4* wr = Wt4 + (size_t)wv * 256 * 64 + lane;
        double acc = 0.0;
#pragma unroll 4
        for (int k4 = 0; k4 < 256; ++k4) {
            float4 xv = xr[k4];
            float4 wq = wr[(size_t)k4 * 64];
            acc += (double)xv.x * wq.x + (double)xv.y * wq.y
                 + (double)xv.z * wq.z + (double)xv.w * wq.w;
        }
        red[wv][lane] = acc;
        __syncthreads();
        if (wv == 0) {
            double v = red[0][lane] + red[1][lane] + red[2][lane] + red[3][lane];
            double m1 = v; int i1 = lane;
#pragma unroll
            for (int off = 32; off; off >>= 1) {
                double ov = __shfl_xor(m1, off); int oi = __shfl_xor(i1, off);
                if (ov > m1 || (ov == m1 && oi < i1)) { m1 = ov; i1 = oi; }
            }
            double m2 = (lane == i1) ? -INFINITY : v; int i2 = lane;
#pragma unroll
            for (int off = 32; off; off >>= 1) {
                double ov = __shfl_xor(m2, off); int oi = __shfl_xor(i2, off);
                if (ov > m2 || (ov == m2 && oi < i2)) { m2 = ov; i2 = oi; }
            }
            if (lane == 0) {
                double e2  = exp(m2 - m1);
                double inv = 1.0 / (1.0 + e2);
                out[2 * tok + 0] = (float)i1;
                out[2 * tok + 1] = (float)i2;
                out[2 * N_TOKENS + 2 * tok + 0] = (float)inv;
                out[2 * N_TOKENS + 2 * tok + 1] = (float)(e2 * inv);
            }
        }
        __syncthreads();
    }
}

// ---------------------------------------------------------------------------
extern "C" void kernel_launch(void* const* d_in, const int* in_sizes, int n_in,
                              void* d_out, int out_size, void* d_ws, size_t ws_size,
                              hipStream_t stream) {
    const float* x = (const float*)d_in[0];
    const float* W = (const float*)d_in[1];
    float* out = (float*)d_out;

    float4* Wt4     = (float4*)d_ws;                             // [0,1MB)
    uint4*  Bpack   = (uint4*)((char*)d_ws + (1u << 20));        // [1MB,2MB)
    float*  partial = (float*)((char*)d_ws + (2u << 20));        // [2MB,10MB)
    int*    flags   = (int*)((char*)d_ws + (10u << 20));         // [10MB,..)

    wt_pack    <<<256, 256, 0, stream>>>(W, Wt4);
    w_pack_bf16<<<128, 256, 0, stream>>>(W, Bpack, flags);
    router_mfma<<<512, 256, 0, stream>>>(x, Bpack, partial);
    finalize   <<<N_TOKENS / 4, 256, 0, stream>>>(partial, out, flags);
    refine     <<<128, 256, 0, stream>>>(x, Wt4, flags, out);
}